// Round 6
// baseline (218.245 us; speedup 1.0000x reference)
//
#include <hip/hip_runtime.h>

#define NVOX 200000
#define KOFF 27
#define CIN 16
#define CMID 32
#define COUT 32
#define EPSBN 1e-3f

typedef _Float16 f16x8 __attribute__((ext_vector_type(8)));
typedef _Float16 f16x4 __attribute__((ext_vector_type(4)));
typedef float f32x16 __attribute__((ext_vector_type(16)));

// ws layout (bytes):
//   [0, 21,600,000)              gatherT int32[KOFF][NVOX]  (-1 = none; gap-filled in k_build)
//   [21,600,000, 34,400,064)     x1h fp16[(NVOX+1)][32]  (conv1 pre-BN out)
//   [34,400,064, 40,800,096)     featsh fp16[(NVOX+1)][16] (row NVOX = zeros)
//   [40,800,096, 40,827,744)     WB1 fp16[27][64][8]   B-frags for 32x32x16 (K=16=CIN)
//   [40,827,744, 40,883,040)     WB2 fp16[27][2][64][8] B-frags (K=32 split in 2)
//   [40,883,040, +512)           stats: sums1[64] | sums2[64]
#define OFF_X1H 21600000
#define OFF_FH  34400064
#define OFF_WB1 40800096
#define OFF_WB2 40827744
#define OFF_ST  40883040

// One pass: rulebook -> gatherT (with -1 gap fill, no memset needed),
// feats->fp16, weight B-frags, zero row, stats zeroing.
// rule_out is ascending within each k (real entries), padding dst = NVOX.
__global__ __launch_bounds__(256) void k_build(const int* __restrict__ rule_in,
                                               const int* __restrict__ rule_out,
                                               const float* __restrict__ feats,
                                               const float* __restrict__ W1,
                                               const float* __restrict__ W2,
                                               int* __restrict__ gatherT,
                                               _Float16* __restrict__ featsh,
                                               _Float16* __restrict__ WB1,
                                               _Float16* __restrict__ WB2,
                                               float* __restrict__ stats) {
  int e = blockIdx.x * 256 + threadIdx.x;
  if (e < KOFF * NVOX) {
    int k = e / NVOX;
    int pos = e - k * NVOX;
    int dst = rule_out[e];
    int ndst = (pos == NVOX - 1) ? NVOX : rule_out[e + 1];
    int* __restrict__ gk = gatherT + k * NVOX;
    if (dst < NVOX) {
      gk[dst] = rule_in[e];
      if (pos == 0) {
        for (int d = 0; d < dst; ++d) gk[d] = -1;
      }
      for (int d = dst + 1; d < ndst; ++d) gk[d] = -1;
    }
  }
  if (e < NVOX * CIN / 4) {
    float4 f = ((const float4*)feats)[e];
    f16x4 h = {(_Float16)f.x, (_Float16)f.y, (_Float16)f.z, (_Float16)f.w};
    ((f16x4*)featsh)[e] = h;
  }
  if (e < KOFF * 512) {  // WB1: lane l holds W1[k][kk=(l>>5)*8+j][n=l&31]
    int j = e & 7, l = (e >> 3) & 63, k = e >> 9;
    int kk = ((l >> 5) << 3) + j;
    int n = l & 31;
    WB1[e] = (_Float16)W1[(k * CIN + kk) * CMID + n];
  }
  if (e < KOFF * 1024) {  // WB2: f selects K-half
    int j = e & 7, l = (e >> 3) & 63, f = (e >> 9) & 1, k = e >> 10;
    int kk = (f << 4) + ((l >> 5) << 3) + j;
    int n = l & 31;
    WB2[e] = (_Float16)W2[(k * CMID + kk) * COUT + n];
  }
  if (e < CIN) featsh[(size_t)NVOX * CIN + e] = (_Float16)0.f;
  if (e < 128) stats[e] = 0.f;
}

// conv1: 32 rows/wave, 1 MFMA (32x32x16, K=16=CIN) per offset.
// Depth-3 explicit pipeline; invalid neighbors read the zero row. Fused BN1 stats.
__global__ __launch_bounds__(512, 4) void k_conv1m(const _Float16* __restrict__ featsh,
                                                   const int* __restrict__ gatherT,
                                                   const uint4* __restrict__ WB1,
                                                   _Float16* __restrict__ x1h,
                                                   float* __restrict__ gsums) {
  __shared__ uint4 wlds[KOFF * 64];  // 27,648 B
  __shared__ float lsum[64];
  int tid = threadIdx.x;
  for (int i = tid; i < KOFF * 64; i += 512) wlds[i] = WB1[i];
  if (tid < 64) lsum[tid] = 0.f;
  __syncthreads();

  int lane = tid & 63, wave = tid >> 6;
  int m = lane & 31, h = lane >> 5;
  int rowbase = blockIdx.x * 256 + wave * 32;
  int row = rowbase + m;
  int rowc = (row < NVOX) ? row : (NVOX - 1);

  int idx[KOFF];
#pragma unroll
  for (int k = 0; k < KOFF; ++k) idx[k] = gatherT[k * NVOX + rowc];

  f16x8 A[3];
#pragma unroll
  for (int p = 0; p < 3; ++p) {
    unsigned s = ((unsigned)idx[p] < (unsigned)NVOX) ? (unsigned)idx[p] : (unsigned)NVOX;
    A[p] = *(const f16x8*)(featsh + (size_t)s * CIN + (h << 3));
  }

  f32x16 c;
#pragma unroll
  for (int i = 0; i < 16; ++i) c[i] = 0.f;

#pragma unroll
  for (int k = 0; k < KOFF; ++k) {
    f16x8 a = A[k % 3];
    if (k + 3 < KOFF) {
      unsigned s = ((unsigned)idx[k + 3] < (unsigned)NVOX) ? (unsigned)idx[k + 3] : (unsigned)NVOX;
      A[k % 3] = *(const f16x8*)(featsh + (size_t)s * CIN + (h << 3));
    }
    f16x8 b = ((const f16x8*)wlds)[k * 64 + lane];
    c = __builtin_amdgcn_mfma_f32_32x32x16_f16(a, b, c, 0, 0, 0);
  }

  // C layout: col = lane&31 (= channel m), row = (r&3) + 8*(r>>2) + 4*h
  float s0 = 0.f, q0 = 0.f;
#pragma unroll
  for (int r = 0; r < 16; ++r) {
    int grow = rowbase + (r & 3) + ((r >> 2) << 3) + (h << 2);
    float mk = (grow < NVOX) ? 1.f : 0.f;
    float v = c[r] * mk;
    s0 += v; q0 += v * v;
    if (grow < NVOX) x1h[(size_t)grow * CMID + m] = (_Float16)c[r];
  }
  s0 += __shfl_xor(s0, 32, 64);
  q0 += __shfl_xor(q0, 32, 64);
  if (lane < 32) {
    atomicAdd(&lsum[m], s0);
    atomicAdd(&lsum[32 + m], q0);
  }
  __syncthreads();
  if (tid < 64) atomicAdd(&gsums[tid], lsum[tid]);
}

// conv2: 32 rows/wave, 2 MFMAs (K=32) per offset. BN1+ReLU applied to gathered
// rows on the fly (packed fp16, validity-masked). Depth-3 pipeline. Fused BN2 stats.
__global__ __launch_bounds__(512, 4) void k_conv2m(const _Float16* __restrict__ x1h,
                                                   const int* __restrict__ gatherT,
                                                   const uint4* __restrict__ WB2,
                                                   const float* __restrict__ sums1,
                                                   const float* __restrict__ gamma1,
                                                   const float* __restrict__ beta1,
                                                   float* __restrict__ out,
                                                   float* __restrict__ gsums) {
  __shared__ uint4 wlds[KOFF * 128];  // 55,296 B
  __shared__ float lsum[64];
  int tid = threadIdx.x;
  for (int i = tid; i < KOFF * 128; i += 512) wlds[i] = WB2[i];
  if (tid < 64) lsum[tid] = 0.f;
  __syncthreads();

  int lane = tid & 63, wave = tid >> 6;
  int m = lane & 31, h = lane >> 5;
  int rowbase = blockIdx.x * 256 + wave * 32;
  int row = rowbase + m;
  int rowc = (row < NVOX) ? row : (NVOX - 1);

  // BN1 scale/shift (fp16) for this lane's channels: a0 -> [8h,8h+8), a1 -> [16+8h,24+8h)
  const float inv_n = 1.0f / (float)NVOX;
  f16x8 sc0, sh0, sc1, sh1;
#pragma unroll
  for (int i = 0; i < 8; ++i) {
    int c0 = 8 * h + i;
    float mu = sums1[c0] * inv_n;
    float var = sums1[32 + c0] * inv_n - mu * mu;
    float s = gamma1[c0] * rsqrtf(var + EPSBN);
    sc0[i] = (_Float16)s; sh0[i] = (_Float16)(beta1[c0] - mu * s);
    int c1 = 16 + 8 * h + i;
    mu = sums1[c1] * inv_n;
    var = sums1[32 + c1] * inv_n - mu * mu;
    s = gamma1[c1] * rsqrtf(var + EPSBN);
    sc1[i] = (_Float16)s; sh1[i] = (_Float16)(beta1[c1] - mu * s);
  }

  int idx[KOFF];
#pragma unroll
  for (int k = 0; k < KOFF; ++k) idx[k] = gatherT[k * NVOX + rowc];

  f16x8 A0[3], A1[3];
#pragma unroll
  for (int p = 0; p < 3; ++p) {
    unsigned s = ((unsigned)idx[p] < (unsigned)NVOX) ? (unsigned)idx[p] : 0u;
    const _Float16* rp = x1h + (size_t)s * CMID + (h << 3);
    A0[p] = *(const f16x8*)rp;
    A1[p] = *(const f16x8*)(rp + 16);
  }

  f32x16 c;
#pragma unroll
  for (int i = 0; i < 16; ++i) c[i] = 0.f;

  const _Float16 zero_h = (_Float16)0.f;
#pragma unroll
  for (int k = 0; k < KOFF; ++k) {
    _Float16 mk = ((unsigned)idx[k] < (unsigned)NVOX) ? (_Float16)1.f : zero_h;
    f16x8 a0 = A0[k % 3], a1 = A1[k % 3];
    f16x8 y0, y1;
#pragma unroll
    for (int i = 0; i < 8; ++i) {
      _Float16 t0 = a0[i] * sc0[i] + sh0[i];
      t0 = (t0 > zero_h) ? t0 : zero_h;
      y0[i] = t0 * mk;
      _Float16 t1 = a1[i] * sc1[i] + sh1[i];
      t1 = (t1 > zero_h) ? t1 : zero_h;
      y1[i] = t1 * mk;
    }
    if (k + 3 < KOFF) {
      unsigned s = ((unsigned)idx[k + 3] < (unsigned)NVOX) ? (unsigned)idx[k + 3] : 0u;
      const _Float16* rp = x1h + (size_t)s * CMID + (h << 3);
      A0[k % 3] = *(const f16x8*)rp;
      A1[k % 3] = *(const f16x8*)(rp + 16);
    }
    f16x8 b0 = ((const f16x8*)wlds)[(k * 2 + 0) * 64 + lane];
    f16x8 b1 = ((const f16x8*)wlds)[(k * 2 + 1) * 64 + lane];
    c = __builtin_amdgcn_mfma_f32_32x32x16_f16(y0, b0, c, 0, 0, 0);
    c = __builtin_amdgcn_mfma_f32_32x32x16_f16(y1, b1, c, 0, 0, 0);
  }

  float s0 = 0.f, q0 = 0.f;
#pragma unroll
  for (int r = 0; r < 16; ++r) {
    int grow = rowbase + (r & 3) + ((r >> 2) << 3) + (h << 2);
    float mk = (grow < NVOX) ? 1.f : 0.f;
    float v = c[r] * mk;
    s0 += v; q0 += v * v;
    if (grow < NVOX) out[(size_t)grow * COUT + m] = c[r];
  }
  s0 += __shfl_xor(s0, 32, 64);
  q0 += __shfl_xor(q0, 32, 64);
  if (lane < 32) {
    atomicAdd(&lsum[m], s0);
    atomicAdd(&lsum[32 + m], q0);
  }
  __syncthreads();
  if (tid < 64) atomicAdd(&gsums[tid], lsum[tid]);
}

// BN2+ReLU in place on fp32 out, finalize fused
__global__ __launch_bounds__(256) void k_bnrelu2(float* __restrict__ out,
                                                 const float* __restrict__ sums,
                                                 const float* __restrict__ gamma,
                                                 const float* __restrict__ beta) {
  int t = blockIdx.x * 256 + threadIdx.x;
  if (t >= NVOX * COUT / 4) return;
  int c = (t & 7) * 4;
  const float inv_n = 1.0f / (float)NVOX;
  float sc[4], sh[4];
#pragma unroll
  for (int i = 0; i < 4; ++i) {
    float mu = sums[c + i] * inv_n;
    float var = sums[32 + c + i] * inv_n - mu * mu;
    float s = gamma[c + i] * rsqrtf(var + EPSBN);
    sc[i] = s; sh[i] = beta[c + i] - mu * s;
  }
  float4* p = (float4*)out + t;
  float4 v = *p;
  v.x = fmaxf(fmaf(v.x, sc[0], sh[0]), 0.f);
  v.y = fmaxf(fmaf(v.y, sc[1], sh[1]), 0.f);
  v.z = fmaxf(fmaf(v.z, sc[2], sh[2]), 0.f);
  v.w = fmaxf(fmaf(v.w, sc[3], sh[3]), 0.f);
  *p = v;
}

extern "C" void kernel_launch(void* const* d_in, const int* in_sizes, int n_in,
                              void* d_out, int out_size, void* d_ws, size_t ws_size,
                              hipStream_t stream) {
  const float* feats  = (const float*)d_in[0];
  const float* W1     = (const float*)d_in[1];
  const float* gamma1 = (const float*)d_in[2];
  const float* beta1  = (const float*)d_in[3];
  const float* W2     = (const float*)d_in[4];
  const float* gamma2 = (const float*)d_in[5];
  const float* beta2  = (const float*)d_in[6];
  const int* rule_in  = (const int*)d_in[7];
  const int* rule_out = (const int*)d_in[8];
  float* out = (float*)d_out;

  int*       gatherT = (int*)d_ws;
  _Float16*  x1h     = (_Float16*)((char*)d_ws + OFF_X1H);
  _Float16*  featsh  = (_Float16*)((char*)d_ws + OFF_FH);
  _Float16*  WB1     = (_Float16*)((char*)d_ws + OFF_WB1);
  _Float16*  WB2     = (_Float16*)((char*)d_ws + OFF_WB2);
  float*     stats   = (float*)((char*)d_ws + OFF_ST);
  // stats: [0:64] sums1, [64:128] sums2

  k_build<<<(KOFF * NVOX + 255) / 256, 256, 0, stream>>>(
      rule_in, rule_out, feats, W1, W2, gatherT, featsh, WB1, WB2, stats);
  k_conv1m<<<782, 512, 0, stream>>>(featsh, gatherT, (const uint4*)WB1, x1h, stats);
  k_conv2m<<<782, 512, 0, stream>>>(x1h, gatherT, (const uint4*)WB2,
                                    stats, gamma1, beta1, out, stats + 64);
  k_bnrelu2<<<(NVOX * COUT / 4 + 255) / 256, 256, 0, stream>>>(out, stats + 64, gamma2, beta2);
}

// Round 7
// 208.784 us; speedup vs baseline: 1.0453x; 1.0453x over previous
//
#include <hip/hip_runtime.h>

#define NVOX 200000
#define KOFF 27
#define CIN 16
#define CMID 32
#define COUT 32
#define EPSBN 1e-3f
#define PD1 8   // conv1 pipeline depth
#define PD2 6   // conv2 pipeline depth

typedef _Float16 f16x8 __attribute__((ext_vector_type(8)));
typedef _Float16 f16x4 __attribute__((ext_vector_type(4)));
typedef float f32x16 __attribute__((ext_vector_type(16)));

// ws layout (bytes):
//   [0, 21,600,000)              gatherT int32[KOFF][NVOX]  (-1 = none; gap-filled in k_build)
//   [21,600,000, 34,400,064)     x1h fp16[(NVOX+1)][32]  (conv1 pre-BN out; BN1+ReLU in place; row NVOX stays 0)
//   [34,400,064, 40,800,096)     featsh fp16[(NVOX+1)][16] (row NVOX = zeros)
//   [40,800,096, 40,827,744)     WB1 fp16[27][64][8]   B-frags for 32x32x16 (K=16=CIN)
//   [40,827,744, 40,883,040)     WB2 fp16[27][2][64][8] B-frags (K=32 split in 2)
//   [40,883,040, +512)           stats: sums1[64] | sums2[64]
#define OFF_X1H 21600000
#define OFF_FH  34400064
#define OFF_WB1 40800096
#define OFF_WB2 40827744
#define OFF_ST  40883040

// One pass: rulebook -> gatherT (-1 gap fill), feats->fp16, weight B-frags,
// zero rows, stats zeroing. rule_out ascending within each k; padding dst = NVOX.
__global__ __launch_bounds__(256) void k_build(const int* __restrict__ rule_in,
                                               const int* __restrict__ rule_out,
                                               const float* __restrict__ feats,
                                               const float* __restrict__ W1,
                                               const float* __restrict__ W2,
                                               int* __restrict__ gatherT,
                                               _Float16* __restrict__ featsh,
                                               _Float16* __restrict__ WB1,
                                               _Float16* __restrict__ WB2,
                                               _Float16* __restrict__ x1h,
                                               float* __restrict__ stats) {
  int e = blockIdx.x * 256 + threadIdx.x;
  if (e < KOFF * NVOX) {
    int k = e / NVOX;
    int pos = e - k * NVOX;
    int dst = rule_out[e];
    int ndst = (pos == NVOX - 1) ? NVOX : rule_out[e + 1];
    int* __restrict__ gk = gatherT + k * NVOX;
    if (dst < NVOX) {
      gk[dst] = rule_in[e];
      if (pos == 0) {
        for (int d = 0; d < dst; ++d) gk[d] = -1;
      }
      for (int d = dst + 1; d < ndst; ++d) gk[d] = -1;
    }
  }
  if (e < NVOX * CIN / 4) {
    float4 f = ((const float4*)feats)[e];
    f16x4 h = {(_Float16)f.x, (_Float16)f.y, (_Float16)f.z, (_Float16)f.w};
    ((f16x4*)featsh)[e] = h;
  }
  if (e < KOFF * 512) {  // WB1: lane l holds W1[k][kk=(l>>5)*8+j][n=l&31]
    int j = e & 7, l = (e >> 3) & 63, k = e >> 9;
    int kk = ((l >> 5) << 3) + j;
    int n = l & 31;
    WB1[e] = (_Float16)W1[(k * CIN + kk) * CMID + n];
  }
  if (e < KOFF * 1024) {  // WB2: f selects K-half
    int j = e & 7, l = (e >> 3) & 63, f = (e >> 9) & 1, k = e >> 10;
    int kk = (f << 4) + ((l >> 5) << 3) + j;
    int n = l & 31;
    WB2[e] = (_Float16)W2[(k * CMID + kk) * COUT + n];
  }
  if (e < CIN) featsh[(size_t)NVOX * CIN + e] = (_Float16)0.f;
  if (e < CMID) x1h[(size_t)NVOX * CMID + e] = (_Float16)0.f;
  if (e < 128) stats[e] = 0.f;
}

// conv1: 32 rows/wave, 1 MFMA (32x32x16, K=16=CIN) per offset.
// Depth-PD1 explicit pipeline; invalid neighbors read the zero row. Fused BN1 stats.
__global__ __launch_bounds__(512, 4) void k_conv1m(const _Float16* __restrict__ featsh,
                                                   const int* __restrict__ gatherT,
                                                   const uint4* __restrict__ WB1,
                                                   _Float16* __restrict__ x1h,
                                                   float* __restrict__ gsums) {
  __shared__ uint4 wlds[KOFF * 64];  // 27,648 B
  __shared__ float lsum[64];
  int tid = threadIdx.x;
  for (int i = tid; i < KOFF * 64; i += 512) wlds[i] = WB1[i];
  if (tid < 64) lsum[tid] = 0.f;
  __syncthreads();

  int lane = tid & 63, wave = tid >> 6;
  int m = lane & 31, h = lane >> 5;
  int rowbase = blockIdx.x * 256 + wave * 32;
  int row = rowbase + m;
  int rowc = (row < NVOX) ? row : (NVOX - 1);

  int idx[KOFF];
#pragma unroll
  for (int k = 0; k < KOFF; ++k) idx[k] = gatherT[k * NVOX + rowc];

  f16x8 A[PD1];
#pragma unroll
  for (int p = 0; p < PD1; ++p) {
    unsigned s = ((unsigned)idx[p] < (unsigned)NVOX) ? (unsigned)idx[p] : (unsigned)NVOX;
    A[p] = *(const f16x8*)(featsh + (size_t)s * CIN + (h << 3));
  }

  f32x16 c;
#pragma unroll
  for (int i = 0; i < 16; ++i) c[i] = 0.f;

#pragma unroll
  for (int k = 0; k < KOFF; ++k) {
    f16x8 a = A[k % PD1];
    if (k + PD1 < KOFF) {
      unsigned s = ((unsigned)idx[k + PD1] < (unsigned)NVOX) ? (unsigned)idx[k + PD1] : (unsigned)NVOX;
      A[k % PD1] = *(const f16x8*)(featsh + (size_t)s * CIN + (h << 3));
    }
    f16x8 b = ((const f16x8*)wlds)[k * 64 + lane];
    c = __builtin_amdgcn_mfma_f32_32x32x16_f16(a, b, c, 0, 0, 0);
  }

  // C layout: col = lane&31 (= channel m), row = (r&3) + 8*(r>>2) + 4*h
  float s0 = 0.f, q0 = 0.f;
#pragma unroll
  for (int r = 0; r < 16; ++r) {
    int grow = rowbase + (r & 3) + ((r >> 2) << 3) + (h << 2);
    float mk = (grow < NVOX) ? 1.f : 0.f;
    float v = c[r] * mk;
    s0 += v; q0 += v * v;
    if (grow < NVOX) x1h[(size_t)grow * CMID + m] = (_Float16)c[r];
  }
  s0 += __shfl_xor(s0, 32, 64);
  q0 += __shfl_xor(q0, 32, 64);
  if (lane < 32) {
    atomicAdd(&lsum[m], s0);
    atomicAdd(&lsum[32 + m], q0);
  }
  __syncthreads();
  if (tid < 64) atomicAdd(&gsums[tid], lsum[tid]);
}

// BN1+ReLU in place on fp16 x1h, finalize fused (reads raw sums). Row NVOX untouched (stays 0).
__global__ __launch_bounds__(256) void k_bnrelu1h(_Float16* __restrict__ x1h,
                                                  const float* __restrict__ sums,
                                                  const float* __restrict__ gamma,
                                                  const float* __restrict__ beta) {
  int t = blockIdx.x * 256 + threadIdx.x;
  if (t >= NVOX * CMID / 8) return;
  int c = (t & 3) * 8;
  const float inv_n = 1.0f / (float)NVOX;
  float sc[8], sh[8];
#pragma unroll
  for (int i = 0; i < 8; ++i) {
    float mu = sums[c + i] * inv_n;
    float var = sums[32 + c + i] * inv_n - mu * mu;
    float s = gamma[c + i] * rsqrtf(var + EPSBN);
    sc[i] = s; sh[i] = beta[c + i] - mu * s;
  }
  f16x8* p = (f16x8*)x1h + t;
  f16x8 v = *p;
#pragma unroll
  for (int i = 0; i < 8; ++i) {
    float x = fmaf((float)v[i], sc[i], sh[i]);
    v[i] = (_Float16)fmaxf(x, 0.f);
  }
  *p = v;
}

// conv2: 32 rows/wave, 2 MFMAs (K=32) per offset, post-BN x1h input,
// invalid -> zero row (no masking needed). Depth-PD2 pipeline. Fused BN2 stats.
__global__ __launch_bounds__(512, 4) void k_conv2m(const _Float16* __restrict__ x1h,
                                                   const int* __restrict__ gatherT,
                                                   const uint4* __restrict__ WB2,
                                                   float* __restrict__ out,
                                                   float* __restrict__ gsums) {
  __shared__ uint4 wlds[KOFF * 128];  // 55,296 B
  __shared__ float lsum[64];
  int tid = threadIdx.x;
  for (int i = tid; i < KOFF * 128; i += 512) wlds[i] = WB2[i];
  if (tid < 64) lsum[tid] = 0.f;
  __syncthreads();

  int lane = tid & 63, wave = tid >> 6;
  int m = lane & 31, h = lane >> 5;
  int rowbase = blockIdx.x * 256 + wave * 32;
  int row = rowbase + m;
  int rowc = (row < NVOX) ? row : (NVOX - 1);

  int idx[KOFF];
#pragma unroll
  for (int k = 0; k < KOFF; ++k) idx[k] = gatherT[k * NVOX + rowc];

  f16x8 A0[PD2], A1[PD2];
#pragma unroll
  for (int p = 0; p < PD2; ++p) {
    unsigned s = ((unsigned)idx[p] < (unsigned)NVOX) ? (unsigned)idx[p] : (unsigned)NVOX;
    const _Float16* rp = x1h + (size_t)s * CMID + (h << 3);
    A0[p] = *(const f16x8*)rp;
    A1[p] = *(const f16x8*)(rp + 16);
  }

  f32x16 c;
#pragma unroll
  for (int i = 0; i < 16; ++i) c[i] = 0.f;

#pragma unroll
  for (int k = 0; k < KOFF; ++k) {
    f16x8 a0 = A0[k % PD2], a1 = A1[k % PD2];
    if (k + PD2 < KOFF) {
      unsigned s = ((unsigned)idx[k + PD2] < (unsigned)NVOX) ? (unsigned)idx[k + PD2] : (unsigned)NVOX;
      const _Float16* rp = x1h + (size_t)s * CMID + (h << 3);
      A0[k % PD2] = *(const f16x8*)rp;
      A1[k % PD2] = *(const f16x8*)(rp + 16);
    }
    f16x8 b0 = ((const f16x8*)wlds)[(k * 2 + 0) * 64 + lane];
    f16x8 b1 = ((const f16x8*)wlds)[(k * 2 + 1) * 64 + lane];
    c = __builtin_amdgcn_mfma_f32_32x32x16_f16(a0, b0, c, 0, 0, 0);
    c = __builtin_amdgcn_mfma_f32_32x32x16_f16(a1, b1, c, 0, 0, 0);
  }

  float s0 = 0.f, q0 = 0.f;
#pragma unroll
  for (int r = 0; r < 16; ++r) {
    int grow = rowbase + (r & 3) + ((r >> 2) << 3) + (h << 2);
    float mk = (grow < NVOX) ? 1.f : 0.f;
    float v = c[r] * mk;
    s0 += v; q0 += v * v;
    if (grow < NVOX) out[(size_t)grow * COUT + m] = c[r];
  }
  s0 += __shfl_xor(s0, 32, 64);
  q0 += __shfl_xor(q0, 32, 64);
  if (lane < 32) {
    atomicAdd(&lsum[m], s0);
    atomicAdd(&lsum[32 + m], q0);
  }
  __syncthreads();
  if (tid < 64) atomicAdd(&gsums[tid], lsum[tid]);
}

// BN2+ReLU in place on fp32 out, finalize fused
__global__ __launch_bounds__(256) void k_bnrelu2(float* __restrict__ out,
                                                 const float* __restrict__ sums,
                                                 const float* __restrict__ gamma,
                                                 const float* __restrict__ beta) {
  int t = blockIdx.x * 256 + threadIdx.x;
  if (t >= NVOX * COUT / 4) return;
  int c = (t & 7) * 4;
  const float inv_n = 1.0f / (float)NVOX;
  float sc[4], sh[4];
#pragma unroll
  for (int i = 0; i < 4; ++i) {
    float mu = sums[c + i] * inv_n;
    float var = sums[32 + c + i] * inv_n - mu * mu;
    float s = gamma[c + i] * rsqrtf(var + EPSBN);
    sc[i] = s; sh[i] = beta[c + i] - mu * s;
  }
  float4* p = (float4*)out + t;
  float4 v = *p;
  v.x = fmaxf(fmaf(v.x, sc[0], sh[0]), 0.f);
  v.y = fmaxf(fmaf(v.y, sc[1], sh[1]), 0.f);
  v.z = fmaxf(fmaf(v.z, sc[2], sh[2]), 0.f);
  v.w = fmaxf(fmaf(v.w, sc[3], sh[3]), 0.f);
  *p = v;
}

extern "C" void kernel_launch(void* const* d_in, const int* in_sizes, int n_in,
                              void* d_out, int out_size, void* d_ws, size_t ws_size,
                              hipStream_t stream) {
  const float* feats  = (const float*)d_in[0];
  const float* W1     = (const float*)d_in[1];
  const float* gamma1 = (const float*)d_in[2];
  const float* beta1  = (const float*)d_in[3];
  const float* W2     = (const float*)d_in[4];
  const float* gamma2 = (const float*)d_in[5];
  const float* beta2  = (const float*)d_in[6];
  const int* rule_in  = (const int*)d_in[7];
  const int* rule_out = (const int*)d_in[8];
  float* out = (float*)d_out;

  int*       gatherT = (int*)d_ws;
  _Float16*  x1h     = (_Float16*)((char*)d_ws + OFF_X1H);
  _Float16*  featsh  = (_Float16*)((char*)d_ws + OFF_FH);
  _Float16*  WB1     = (_Float16*)((char*)d_ws + OFF_WB1);
  _Float16*  WB2     = (_Float16*)((char*)d_ws + OFF_WB2);
  float*     stats   = (float*)((char*)d_ws + OFF_ST);
  // stats: [0:64] sums1, [64:128] sums2

  k_build<<<(KOFF * NVOX + 255) / 256, 256, 0, stream>>>(
      rule_in, rule_out, feats, W1, W2, gatherT, featsh, WB1, WB2, x1h, stats);
  k_conv1m<<<782, 512, 0, stream>>>(featsh, gatherT, (const uint4*)WB1, x1h, stats);
  k_bnrelu1h<<<(NVOX * CMID / 8 + 255) / 256, 256, 0, stream>>>(x1h, stats, gamma1, beta1);
  k_conv2m<<<782, 512, 0, stream>>>(x1h, gatherT, (const uint4*)WB2, out, stats + 64);
  k_bnrelu2<<<(NVOX * COUT / 4 + 255) / 256, 256, 0, stream>>>(out, stats + 64, gamma2, beta2);
}